// Round 5
// baseline (535.791 us; speedup 1.0000x reference)
//
#include <hip/hip_runtime.h>
#include <vector>
#include <algorithm>
#include <utility>

typedef unsigned long long u64;
typedef unsigned int u32;

#define NTRIP 110592              // 48^3 distinct (c0,c1,c2)
#define NBINS (NTRIP * 64)        // 7,077,888 possible point keys
#define SCAN_T 256
#define SCAN_E 8
#define SCAN_CHUNK 2048           // bins per scan block
#define NCHUNKS (NBINS / SCAN_CHUNK)  // 3456
#define S2_E 16                   // level-2 scan: 256*16 = 4096 >= 3456

// ======== host-side: rank table for the 110,592 triple-hashes ========
// full hash = fnv3p(c0,c1,c2) ^ c3, c3 < 64 flips only low 6 bits.
// rank48[tau] = (rank_of_hash << 6) | (hash & 63)
static u32 g_rank48[NTRIP];
namespace {
struct RankInit {
    RankInit() {
        std::vector<std::pair<u64, u32>> v(NTRIP);
        for (u32 t = 0; t < NTRIP; t++) {
            u64 h = 14695981039346656037ull;
            const u64 P = 1099511628211ull;
            h *= P; h ^= (u64)(t / 2304);
            h *= P; h ^= (u64)((t % 2304) / 48);
            h *= P; h ^= (u64)(t % 48);
            h *= P;
            v[t] = {h, t};
        }
        std::sort(v.begin(), v.end());
        for (u32 p = 0; p < NTRIP; p++)
            g_rank48[v[p].second] = (p << 6) | (u32)(v[p].first & 63ull);
    }
};
static RankInit g_rank_init;
}

// invrank[rank] = (tau<<6) | (t&63)  -- inverse of rank48
__global__ void k_invrank(const u32* __restrict__ rank48, u32* __restrict__ invrank) {
    int tau = blockIdx.x * blockDim.x + threadIdx.x;
    if (tau >= NTRIP) return;
    u32 r = rank48[tau];
    invrank[r >> 6] = ((u32)tau << 6) | (r & 63u);
}

// ======== point keys + histogram ========
__global__ void k_pkeys(const int* __restrict__ coords, const u32* __restrict__ rank48,
                        u32* __restrict__ pos, u32* __restrict__ pkey, int N) {
    int i = blockIdx.x * blockDim.x + threadIdx.x;
    if (i >= N) return;
    int4 c = ((const int4*)coords)[i];
    u32 tau = (u32)c.x * 2304u + (u32)c.y * 48u + (u32)c.z;
    u32 kk = rank48[tau] ^ (u32)c.w;
    pkey[i] = kk;
    atomicAdd(&pos[kk], 1u);
}

// ======== scan pass A: per-chunk (count,flag) totals ========
__global__ void k_scan2A(const u32* __restrict__ pos, u64* __restrict__ lvl2) {
    __shared__ u64 s[SCAN_T];
    int tid = threadIdx.x;
    int base = blockIdx.x * SCAN_CHUNK + tid * SCAN_E;
    u64 run = 0;
#pragma unroll
    for (int e = 0; e < SCAN_E; e++) {
        u32 c = pos[base + e];
        run += (u64)c | ((u64)(c ? 1u : 0u) << 32);
    }
    s[tid] = run;
    __syncthreads();
    for (int off = SCAN_T / 2; off > 0; off >>= 1) {
        if (tid < off) s[tid] += s[tid + off];
        __syncthreads();
    }
    if (tid == 0) lvl2[blockIdx.x] = s[0];
}

// ======== level-2: exclusive pair-scan over chunks + num_voxels ========
__global__ void k_scan2_single(u64* data, int n, u32* __restrict__ nvslot) {
    __shared__ u64 s[SCAN_T];
    int tid = threadIdx.x;
    int idx0 = tid * S2_E;
    u64 v[S2_E], o[S2_E];
    u64 run = 0;
#pragma unroll
    for (int k = 0; k < S2_E; k++) {
        int idx = idx0 + k;
        u64 x = (idx < n) ? data[idx] : 0;
        o[k] = x; run += x; v[k] = run;
    }
    s[tid] = run;
    __syncthreads();
    for (int off = 1; off < SCAN_T; off <<= 1) {
        u64 t = (tid >= off) ? s[tid - off] : 0;
        __syncthreads();
        s[tid] += t;
        __syncthreads();
    }
    u64 tbase = s[tid] - run;
#pragma unroll
    for (int k = 0; k < S2_E; k++) {
        int idx = idx0 + k;
        if (idx < n) data[idx] = tbase + v[k] - o[k];
    }
    if (tid == SCAN_T - 1) nvslot[0] = (u32)(s[SCAN_T - 1] >> 32);
}

// ======== scan pass B: finalize pos (exclusive count scan) + voxkey ========
__global__ void k_scan2B(u32* __restrict__ pos, const u64* __restrict__ lvl2,
                         u32* __restrict__ voxkey) {
    __shared__ u64 s[SCAN_T];
    int tid = threadIdx.x;
    int base = blockIdx.x * SCAN_CHUNK + tid * SCAN_E;
    u32 cv[SCAN_E];
    u64 incl[SCAN_E];
    u64 run = 0;
#pragma unroll
    for (int e = 0; e < SCAN_E; e++) {
        u32 c = pos[base + e];
        cv[e] = c;
        run += (u64)c | ((u64)(c ? 1u : 0u) << 32);
        incl[e] = run;
    }
    s[tid] = run;
    __syncthreads();
    for (int off = 1; off < SCAN_T; off <<= 1) {
        u64 t = (tid >= off) ? s[tid - off] : 0;
        __syncthreads();
        s[tid] += t;
        __syncthreads();
    }
    u64 tot = s[tid] - run + lvl2[blockIdx.x];
#pragma unroll
    for (int e = 0; e < SCAN_E; e++) {
        u64 v = tot + incl[e];
        pos[base + e] = (u32)v - cv[e];                      // global exclusive count scan
        if (cv[e]) voxkey[(u32)(v >> 32) - 1u] = (u32)(base + e);  // gid -> bin
    }
}

// ======== per-point scatter of indices ========
__global__ void k_scatter(const u32* __restrict__ pkey, u32* __restrict__ pos,
                          u32* __restrict__ sidx, int N) {
    int i = blockIdx.x * blockDim.x + threadIdx.x;
    if (i >= N) return;
    u32 kk = pkey[i];
    u32 p = atomicAdd(&pos[kk], 1u);
    sidx[p] = (u32)i;
}

// ======== per-voxel outputs + padding zeros (thread per output row) ========
__global__ void k_vox(const u32* __restrict__ pos, const u32* __restrict__ voxkey,
                      const u32* __restrict__ sidx, const u32* __restrict__ invrank,
                      const float* __restrict__ feats, const u32* __restrict__ nvslot,
                      float* __restrict__ vox_feats, float* __restrict__ vox_coords,
                      float* __restrict__ v2p, float* __restrict__ nvox, int N) {
    int t = blockIdx.x * blockDim.x + threadIdx.x;
    if (t >= N) return;
    u32 nv = nvslot[0];
    if (t == 0) nvox[0] = (float)nv;
    if ((u32)t >= nv) {
        // padding rows: zeros
        float4 z = {0, 0, 0, 0};
        float4* vf = (float4*)(vox_feats + (size_t)t * 16);
        vf[0] = z; vf[1] = z; vf[2] = z; vf[3] = z;
        *(float4*)(vox_coords + (size_t)t * 4) = z;
        return;
    }
    u32 kk = voxkey[t];
    u32 endv = pos[kk];                 // inclusive after scatter
    u32 start = kk ? pos[kk - 1] : 0u;
    u32 c = endv - start;
    float4 a0 = {0, 0, 0, 0}, a1 = {0, 0, 0, 0}, a2 = {0, 0, 0, 0}, a3 = {0, 0, 0, 0};
    // sum in ascending original-index order (matches reference's sequential segment sum)
    int last = -1;
    for (u32 it = 0; it < c; it++) {
        int mn = 0x7fffffff;
        for (u32 j = 0; j < c; j++) {
            int id = (int)sidx[start + j];
            if (id > last && id < mn) mn = id;
        }
        last = mn;
        v2p[mn] = (float)t;
        const float4* f = (const float4*)(feats + (size_t)mn * 16);
        float4 v0 = f[0], v1 = f[1], v2 = f[2], v3 = f[3];
        a0.x += v0.x; a0.y += v0.y; a0.z += v0.z; a0.w += v0.w;
        a1.x += v1.x; a1.y += v1.y; a1.z += v1.z; a1.w += v1.w;
        a2.x += v2.x; a2.y += v2.y; a2.z += v2.z; a2.w += v2.w;
        a3.x += v3.x; a3.y += v3.y; a3.z += v3.z; a3.w += v3.w;
    }
    float fc = (float)c;
    float4* vf = (float4*)(vox_feats + (size_t)t * 16);
    vf[0] = make_float4(a0.x / fc, a0.y / fc, a0.z / fc, a0.w / fc);
    vf[1] = make_float4(a1.x / fc, a1.y / fc, a1.z / fc, a1.w / fc);
    vf[2] = make_float4(a2.x / fc, a2.y / fc, a2.z / fc, a2.w / fc);
    vf[3] = make_float4(a3.x / fc, a3.y / fc, a3.z / fc, a3.w / fc);
    // reconstruct coords from key (all points in a voxel share coords; no 58-bit collisions)
    u32 iv = invrank[kk >> 6];
    u32 tau = iv >> 6;
    u32 c3 = (kk ^ iv) & 63u;
    *(float4*)(vox_coords + (size_t)t * 4) =
        make_float4((float)(tau / 2304u), (float)((tau % 2304u) / 48u),
                    (float)(tau % 48u), (float)c3);
}

extern "C" void kernel_launch(void* const* d_in, const int* in_sizes, int n_in,
                              void* d_out, int out_size, void* d_ws, size_t ws_size,
                              hipStream_t stream) {
    const int* coords = (const int*)d_in[0];
    const float* feats = (const float*)d_in[1];
    int N = in_sizes[0] / 4;

    float* out = (float*)d_out;
    float* vox_feats = out;                      // N*16
    float* vox_coords = out + (size_t)N * 16;    // N*4
    float* v2p = vox_coords + (size_t)N * 4;     // N
    float* nvox = v2p + (size_t)N;               // 1

    char* w = (char*)d_ws;
    u32* pos = (u32*)w;        w += (size_t)NBINS * 4;   // 28.3 MB
    u32* pkey = (u32*)w;       w += (size_t)N * 4;
    u32* sidx = (u32*)w;       w += (size_t)N * 4;
    u32* voxkey = (u32*)w;     w += (size_t)N * 4;
    u32* rank48_d = (u32*)w;   w += (size_t)NTRIP * 4;
    u32* invrank_d = (u32*)w;  w += (size_t)NTRIP * 4;
    u64* lvl2 = (u64*)w;       w += (size_t)4096 * 8;
    u32* nvslot = (u32*)w;     w += 256;

    hipMemcpyAsync(rank48_d, g_rank48, sizeof(g_rank48), hipMemcpyHostToDevice, stream);
    hipMemsetAsync(pos, 0, (size_t)NBINS * 4, stream);

    int blocksN = (N + 255) / 256;
    int blocksT = (NTRIP + 255) / 256;

    k_invrank<<<blocksT, 256, 0, stream>>>(rank48_d, invrank_d);
    k_pkeys<<<blocksN, 256, 0, stream>>>(coords, rank48_d, pos, pkey, N);
    k_scan2A<<<NCHUNKS, SCAN_T, 0, stream>>>(pos, lvl2);
    k_scan2_single<<<1, SCAN_T, 0, stream>>>(lvl2, NCHUNKS, nvslot);
    k_scan2B<<<NCHUNKS, SCAN_T, 0, stream>>>(pos, lvl2, voxkey);
    k_scatter<<<blocksN, 256, 0, stream>>>(pkey, pos, sidx, N);
    k_vox<<<blocksN, 256, 0, stream>>>(pos, voxkey, sidx, invrank_d, feats, nvslot,
                                       vox_feats, vox_coords, v2p, nvox, N);
}

// Round 6
// 482.273 us; speedup vs baseline: 1.1110x; 1.1110x over previous
//
#include <hip/hip_runtime.h>
#include <vector>
#include <algorithm>
#include <utility>

typedef unsigned long long u64;
typedef unsigned int u32;

#define NTRIP 110592              // 48^3 distinct (c0,c1,c2)
#define NBINS (NTRIP * 64)        // 7,077,888 possible point keys (23 bits)
#define KMASK 0x7FFFFFu
#define SCAN_T 256
#define SCAN_E 8
#define SCAN_CHUNK 2048           // bins per scan block
#define NCHUNKS (NBINS / SCAN_CHUNK)  // 3456
#define S2_E 16                   // level-2 scan: 256*16 = 4096 >= 3456

// ======== host-side: rank table for the 110,592 triple-hashes ========
// full hash = fnv3p(c0,c1,c2) ^ c3 (c3 < 64 flips only low 6 bits).
// rank48[tau] = (rank_of_hash << 6) | (hash & 63)
static u32 g_rank48[NTRIP];
namespace {
struct RankInit {
    RankInit() {
        std::vector<std::pair<u64, u32>> v(NTRIP);
        for (u32 t = 0; t < NTRIP; t++) {
            u64 h = 14695981039346656037ull;
            const u64 P = 1099511628211ull;
            h *= P; h ^= (u64)(t / 2304);
            h *= P; h ^= (u64)((t % 2304) / 48);
            h *= P; h ^= (u64)(t % 48);
            h *= P;
            v[t] = {h, t};
        }
        std::sort(v.begin(), v.end());
        for (u32 p = 0; p < NTRIP; p++)
            g_rank48[v[p].second] = (p << 6) | (u32)(v[p].first & 63ull);
    }
};
static RankInit g_rank_init;
}

// invrank[rank] = (tau<<6) | (t&63)  -- inverse of rank48
__global__ void k_invrank(const u32* __restrict__ rank48, u32* __restrict__ invrank) {
    int tau = blockIdx.x * blockDim.x + threadIdx.x;
    if (tau >= NTRIP) return;
    u32 r = rank48[tau];
    invrank[r >> 6] = ((u32)tau << 6) | (r & 63u);
}

// ======== point keys + histogram ========
__global__ void k_pkeys(const int* __restrict__ coords, const u32* __restrict__ rank48,
                        u32* __restrict__ pos, u32* __restrict__ pkey, int N) {
    int i = blockIdx.x * blockDim.x + threadIdx.x;
    if (i >= N) return;
    int4 c = ((const int4*)coords)[i];
    u32 tau = (u32)c.x * 2304u + (u32)c.y * 48u + (u32)c.z;
    u32 kk = rank48[tau] ^ (u32)c.w;
    pkey[i] = kk;
    atomicAdd(&pos[kk], 1u);
}

// ======== scan pass A: per-chunk (count,flag) totals ========
__global__ void k_scan2A(const u32* __restrict__ pos, u64* __restrict__ lvl2) {
    __shared__ u64 s[SCAN_T];
    int tid = threadIdx.x;
    int base = blockIdx.x * SCAN_CHUNK + tid * SCAN_E;
    u64 run = 0;
#pragma unroll
    for (int e = 0; e < SCAN_E; e++) {
        u32 c = pos[base + e];
        run += (u64)c | ((u64)(c ? 1u : 0u) << 32);
    }
    s[tid] = run;
    __syncthreads();
    for (int off = SCAN_T / 2; off > 0; off >>= 1) {
        if (tid < off) s[tid] += s[tid + off];
        __syncthreads();
    }
    if (tid == 0) lvl2[blockIdx.x] = s[0];
}

// ======== level-2: exclusive pair-scan over chunks + num_voxels ========
__global__ void k_scan2_single(u64* data, int n, u32* __restrict__ nvslot) {
    __shared__ u64 s[SCAN_T];
    int tid = threadIdx.x;
    int idx0 = tid * S2_E;
    u64 v[S2_E], o[S2_E];
    u64 run = 0;
#pragma unroll
    for (int k = 0; k < S2_E; k++) {
        int idx = idx0 + k;
        u64 x = (idx < n) ? data[idx] : 0;
        o[k] = x; run += x; v[k] = run;
    }
    s[tid] = run;
    __syncthreads();
    for (int off = 1; off < SCAN_T; off <<= 1) {
        u64 t = (tid >= off) ? s[tid - off] : 0;
        __syncthreads();
        s[tid] += t;
        __syncthreads();
    }
    u64 tbase = s[tid] - run;
#pragma unroll
    for (int k = 0; k < S2_E; k++) {
        int idx = idx0 + k;
        if (idx < n) data[idx] = tbase + v[k] - o[k];
    }
    if (tid == SCAN_T - 1) nvslot[0] = (u32)(s[SCAN_T - 1] >> 32);
}

// ======== scan pass B: pos -> exclusive count scan; emit voxkey/voxstart ========
__global__ void k_scan2B(u32* __restrict__ pos, const u64* __restrict__ lvl2,
                         u32* __restrict__ voxkey, u32* __restrict__ voxstart) {
    __shared__ u64 s[SCAN_T];
    int tid = threadIdx.x;
    int base = blockIdx.x * SCAN_CHUNK + tid * SCAN_E;
    u32 cv[SCAN_E];
    u64 incl[SCAN_E];
    u64 run = 0;
#pragma unroll
    for (int e = 0; e < SCAN_E; e++) {
        u32 c = pos[base + e];
        cv[e] = c;
        run += (u64)c | ((u64)(c ? 1u : 0u) << 32);
        incl[e] = run;
    }
    s[tid] = run;
    __syncthreads();
    for (int off = 1; off < SCAN_T; off <<= 1) {
        u64 t = (tid >= off) ? s[tid - off] : 0;
        __syncthreads();
        s[tid] += t;
        __syncthreads();
    }
    u64 tot = s[tid] - run + lvl2[blockIdx.x];
#pragma unroll
    for (int e = 0; e < SCAN_E; e++) {
        u64 v = tot + incl[e];
        u32 excl = (u32)v - cv[e];
        pos[base + e] = excl;  // global exclusive count scan
        if (cv[e]) {
            u32 gid = (u32)(v >> 32) - 1u;
            u32 cnt = cv[e] > 511u ? 511u : cv[e];
            voxkey[gid] = (u32)(base + e) | (cnt << 23);  // bin | count
            voxstart[gid] = excl;
        }
    }
}

// ======== per-point: gid via binary search, v2p, scatter index ========
__global__ void k_points2(const u32* __restrict__ pkey, const u32* __restrict__ voxkey,
                          const u32* __restrict__ voxstart, u32* __restrict__ pos,
                          const u32* __restrict__ nvslot, u32* __restrict__ sidx,
                          float* __restrict__ v2p, int N) {
    int i = blockIdx.x * blockDim.x + threadIdx.x;
    if (i >= N) return;
    u32 kk = pkey[i];
    u32 lo = 0, hi = nvslot[0];
    while (lo < hi) {
        u32 mid = (lo + hi) >> 1;
        if ((voxkey[mid] & KMASK) < kk) lo = mid + 1;
        else hi = mid;
    }
    u32 gid = lo;
    v2p[i] = (float)gid;
    u32 cnt = voxkey[gid] >> 23;
    if (cnt == 1u) {
        sidx[voxstart[gid]] = (u32)i;            // singleton: no atomic
    } else {
        u32 p = atomicAdd(&pos[kk], 1u);         // pos[kk] starts at exclusive offset
        sidx[p] = (u32)i;
    }
}

// ======== per-voxel outputs + padding zeros (thread per output row) ========
__global__ void k_vox(const u32* __restrict__ voxkey, const u32* __restrict__ voxstart,
                      const u32* __restrict__ sidx, const u32* __restrict__ invrank,
                      const float* __restrict__ feats, const u32* __restrict__ nvslot,
                      float* __restrict__ vox_feats, float* __restrict__ vox_coords,
                      float* __restrict__ nvox, int N) {
    int t = blockIdx.x * blockDim.x + threadIdx.x;
    if (t >= N) return;
    u32 nv = nvslot[0];
    if (t == 0) nvox[0] = (float)nv;
    if ((u32)t >= nv) {
        float4 z = {0, 0, 0, 0};
        float4* vf = (float4*)(vox_feats + (size_t)t * 16);
        vf[0] = z; vf[1] = z; vf[2] = z; vf[3] = z;
        *(float4*)(vox_coords + (size_t)t * 4) = z;
        return;
    }
    u32 vk = voxkey[t];
    u32 kk = vk & KMASK;
    u32 c = vk >> 23;
    u32 start = voxstart[t];
    float4 a0 = {0, 0, 0, 0}, a1 = {0, 0, 0, 0}, a2 = {0, 0, 0, 0}, a3 = {0, 0, 0, 0};
    // sum in ascending original-index order (bit-exact vs reference segment_sum)
    int last = -1;
    for (u32 it = 0; it < c; it++) {
        int mn = 0x7fffffff;
        for (u32 j = 0; j < c; j++) {
            int id = (int)sidx[start + j];
            if (id > last && id < mn) mn = id;
        }
        last = mn;
        const float4* f = (const float4*)(feats + (size_t)mn * 16);
        float4 v0 = f[0], v1 = f[1], v2 = f[2], v3 = f[3];
        a0.x += v0.x; a0.y += v0.y; a0.z += v0.z; a0.w += v0.w;
        a1.x += v1.x; a1.y += v1.y; a1.z += v1.z; a1.w += v1.w;
        a2.x += v2.x; a2.y += v2.y; a2.z += v2.z; a2.w += v2.w;
        a3.x += v3.x; a3.y += v3.y; a3.z += v3.z; a3.w += v3.w;
    }
    float fc = (float)c;
    float4* vf = (float4*)(vox_feats + (size_t)t * 16);
    vf[0] = make_float4(a0.x / fc, a0.y / fc, a0.z / fc, a0.w / fc);
    vf[1] = make_float4(a1.x / fc, a1.y / fc, a1.z / fc, a1.w / fc);
    vf[2] = make_float4(a2.x / fc, a2.y / fc, a2.z / fc, a2.w / fc);
    vf[3] = make_float4(a3.x / fc, a3.y / fc, a3.z / fc, a3.w / fc);
    // reconstruct coords from key
    u32 iv = invrank[kk >> 6];
    u32 tau = iv >> 6;
    u32 c3 = (kk ^ iv) & 63u;
    *(float4*)(vox_coords + (size_t)t * 4) =
        make_float4((float)(tau / 2304u), (float)((tau % 2304u) / 48u),
                    (float)(tau % 48u), (float)c3);
}

extern "C" void kernel_launch(void* const* d_in, const int* in_sizes, int n_in,
                              void* d_out, int out_size, void* d_ws, size_t ws_size,
                              hipStream_t stream) {
    const int* coords = (const int*)d_in[0];
    const float* feats = (const float*)d_in[1];
    int N = in_sizes[0] / 4;

    float* out = (float*)d_out;
    float* vox_feats = out;                      // N*16
    float* vox_coords = out + (size_t)N * 16;    // N*4
    float* v2p = vox_coords + (size_t)N * 4;     // N
    float* nvox = v2p + (size_t)N;               // 1

    char* w = (char*)d_ws;
    u32* pos = (u32*)w;        w += (size_t)NBINS * 4;   // 28.3 MB
    u32* pkey = (u32*)w;       w += (size_t)N * 4;
    u32* sidx = (u32*)w;       w += (size_t)N * 4;
    u32* voxkey = (u32*)w;     w += (size_t)N * 4;
    u32* voxstart = (u32*)w;   w += (size_t)N * 4;
    u32* rank48_d = (u32*)w;   w += (size_t)NTRIP * 4;
    u32* invrank_d = (u32*)w;  w += (size_t)NTRIP * 4;
    u64* lvl2 = (u64*)w;       w += (size_t)4096 * 8;
    u32* nvslot = (u32*)w;     w += 256;

    hipMemcpyAsync(rank48_d, g_rank48, sizeof(g_rank48), hipMemcpyHostToDevice, stream);
    hipMemsetAsync(pos, 0, (size_t)NBINS * 4, stream);

    int blocksN = (N + 255) / 256;
    int blocksT = (NTRIP + 255) / 256;

    k_invrank<<<blocksT, 256, 0, stream>>>(rank48_d, invrank_d);
    k_pkeys<<<blocksN, 256, 0, stream>>>(coords, rank48_d, pos, pkey, N);
    k_scan2A<<<NCHUNKS, SCAN_T, 0, stream>>>(pos, lvl2);
    k_scan2_single<<<1, SCAN_T, 0, stream>>>(lvl2, NCHUNKS, nvslot);
    k_scan2B<<<NCHUNKS, SCAN_T, 0, stream>>>(pos, lvl2, voxkey, voxstart);
    k_points2<<<blocksN, 256, 0, stream>>>(pkey, voxkey, voxstart, pos, nvslot, sidx, v2p, N);
    k_vox<<<blocksN, 256, 0, stream>>>(voxkey, voxstart, sidx, invrank_d, feats, nvslot,
                                       vox_feats, vox_coords, nvox, N);
}

// Round 7
// 402.879 us; speedup vs baseline: 1.3299x; 1.1971x over previous
//
#include <hip/hip_runtime.h>
#include <vector>
#include <algorithm>
#include <utility>

typedef unsigned long long u64;
typedef unsigned int u32;

#define NTRIP 110592              // 48^3 distinct (c0,c1,c2)
#define NBINS (NTRIP * 64)        // 7,077,888 possible point keys (23 bits)
#define KMASK 0x7FFFFFu
#define SCAN_T 256
#define SCAN_E 8
#define SCAN_CHUNK 2048           // bins per scan block
#define NCHUNKS (NBINS / SCAN_CHUNK)  // 3456
#define S2_E 16                   // level-2 scan: 256*16 = 4096 >= 3456

// ======== host-side: rank table for the 110,592 triple-hashes ========
// full hash = fnv3p(c0,c1,c2) ^ c3 (c3 < 64 flips only low 6 bits).
// rank48[tau] = (rank_of_hash << 6) | (hash & 63)
static u32 g_rank48[NTRIP];
namespace {
struct RankInit {
    RankInit() {
        std::vector<std::pair<u64, u32>> v(NTRIP);
        for (u32 t = 0; t < NTRIP; t++) {
            u64 h = 14695981039346656037ull;
            const u64 P = 1099511628211ull;
            h *= P; h ^= (u64)(t / 2304);
            h *= P; h ^= (u64)((t % 2304) / 48);
            h *= P; h ^= (u64)(t % 48);
            h *= P;
            v[t] = {h, t};
        }
        std::sort(v.begin(), v.end());
        for (u32 p = 0; p < NTRIP; p++)
            g_rank48[v[p].second] = (p << 6) | (u32)(v[p].first & 63ull);
    }
};
static RankInit g_rank_init;
}

// invrank[rank] = (tau<<6) | (t&63)  -- inverse of rank48
__global__ void k_invrank(const u32* __restrict__ rank48, u32* __restrict__ invrank) {
    int tau = blockIdx.x * blockDim.x + threadIdx.x;
    if (tau >= NTRIP) return;
    u32 r = rank48[tau];
    invrank[r >> 6] = ((u32)tau << 6) | (r & 63u);
}

// ======== point keys + histogram ========
__global__ void k_pkeys(const int* __restrict__ coords, const u32* __restrict__ rank48,
                        u32* __restrict__ pos, u32* __restrict__ pkey, int N) {
    int i = blockIdx.x * blockDim.x + threadIdx.x;
    if (i >= N) return;
    int4 c = ((const int4*)coords)[i];
    u32 tau = (u32)c.x * 2304u + (u32)c.y * 48u + (u32)c.z;
    u32 kk = rank48[tau] ^ (u32)c.w;
    pkey[i] = kk;
    atomicAdd(&pos[kk], 1u);
}

// ======== scan pass A: per-chunk (count,flag) totals ========
__global__ void k_scan2A(const u32* __restrict__ pos, u64* __restrict__ lvl2) {
    __shared__ u64 s[SCAN_T];
    int tid = threadIdx.x;
    int base = blockIdx.x * SCAN_CHUNK + tid * SCAN_E;
    u64 run = 0;
#pragma unroll
    for (int e = 0; e < SCAN_E; e++) {
        u32 c = pos[base + e];
        run += (u64)c | ((u64)(c ? 1u : 0u) << 32);
    }
    s[tid] = run;
    __syncthreads();
    for (int off = SCAN_T / 2; off > 0; off >>= 1) {
        if (tid < off) s[tid] += s[tid + off];
        __syncthreads();
    }
    if (tid == 0) lvl2[blockIdx.x] = s[0];
}

// ======== level-2: exclusive pair-scan over chunks + num_voxels ========
__global__ void k_scan2_single(u64* data, int n, u32* __restrict__ nvslot) {
    __shared__ u64 s[SCAN_T];
    int tid = threadIdx.x;
    int idx0 = tid * S2_E;
    u64 v[S2_E], o[S2_E];
    u64 run = 0;
#pragma unroll
    for (int k = 0; k < S2_E; k++) {
        int idx = idx0 + k;
        u64 x = (idx < n) ? data[idx] : 0;
        o[k] = x; run += x; v[k] = run;
    }
    s[tid] = run;
    __syncthreads();
    for (int off = 1; off < SCAN_T; off <<= 1) {
        u64 t = (tid >= off) ? s[tid - off] : 0;
        __syncthreads();
        s[tid] += t;
        __syncthreads();
    }
    u64 tbase = s[tid] - run;
#pragma unroll
    for (int k = 0; k < S2_E; k++) {
        int idx = idx0 + k;
        if (idx < n) data[idx] = tbase + v[k] - o[k];
    }
    if (tid == SCAN_T - 1) nvslot[0] = (u32)(s[SCAN_T - 1] >> 32);
}

// ======== scan pass B: pos -> inclusive FLAG scan (gid map, in place);
//          voxmeta[gid] = start | (bin|cnt<<23)<<32 ========
__global__ void k_scan2B(u32* __restrict__ pos, const u64* __restrict__ lvl2,
                         u64* __restrict__ voxmeta) {
    __shared__ u64 s[SCAN_T];
    int tid = threadIdx.x;
    int base = blockIdx.x * SCAN_CHUNK + tid * SCAN_E;
    u32 cv[SCAN_E];
    u64 incl[SCAN_E];
    u64 run = 0;
#pragma unroll
    for (int e = 0; e < SCAN_E; e++) {
        u32 c = pos[base + e];
        cv[e] = c;
        run += (u64)c | ((u64)(c ? 1u : 0u) << 32);
        incl[e] = run;
    }
    s[tid] = run;
    __syncthreads();
    for (int off = 1; off < SCAN_T; off <<= 1) {
        u64 t = (tid >= off) ? s[tid - off] : 0;
        __syncthreads();
        s[tid] += t;
        __syncthreads();
    }
    u64 tot = s[tid] - run + lvl2[blockIdx.x];
#pragma unroll
    for (int e = 0; e < SCAN_E; e++) {
        u64 v = tot + incl[e];
        u32 flag_incl = (u32)(v >> 32);
        pos[base + e] = flag_incl;               // gid map: gid = pos[bin]-1 for occupied
        if (cv[e]) {
            u32 excl = (u32)v - cv[e];           // exclusive count scan = segment start
            u32 cnt = cv[e] > 511u ? 511u : cv[e];
            voxmeta[flag_incl - 1u] =
                (u64)excl | ((u64)((u32)(base + e) | (cnt << 23)) << 32);
        }
    }
}

// ======== per-point: gid via table, v2p, scatter index ========
__global__ void k_points2(const u32* __restrict__ pkey, const u32* __restrict__ pos,
                          const u64* __restrict__ voxmeta, u32* __restrict__ vcount,
                          u32* __restrict__ sidx, float* __restrict__ v2p, int N) {
    int i = blockIdx.x * blockDim.x + threadIdx.x;
    if (i >= N) return;
    u32 kk = pkey[i];
    u32 gid = pos[kk] - 1u;
    v2p[i] = (float)gid;
    u64 meta = voxmeta[gid];
    u32 start = (u32)meta;
    u32 cnt = (u32)(meta >> 55);
    u32 slot = start;
    if (cnt != 1u) slot += atomicAdd(&vcount[gid], 1u);
    sidx[slot] = (u32)i;
}

// ======== per-voxel outputs + padding zeros (thread per output row) ========
__global__ void k_vox(const u64* __restrict__ voxmeta, const u32* __restrict__ sidx,
                      const u32* __restrict__ invrank, const float* __restrict__ feats,
                      const u32* __restrict__ nvslot, float* __restrict__ vox_feats,
                      float* __restrict__ vox_coords, float* __restrict__ nvox, int N) {
    int t = blockIdx.x * blockDim.x + threadIdx.x;
    if (t >= N) return;
    u32 nv = nvslot[0];
    if (t == 0) nvox[0] = (float)nv;
    if ((u32)t >= nv) {
        float4 z = {0, 0, 0, 0};
        float4* vf = (float4*)(vox_feats + (size_t)t * 16);
        vf[0] = z; vf[1] = z; vf[2] = z; vf[3] = z;
        *(float4*)(vox_coords + (size_t)t * 4) = z;
        return;
    }
    u64 meta = voxmeta[t];
    u32 start = (u32)meta;
    u32 vk = (u32)(meta >> 32);
    u32 kk = vk & KMASK;
    u32 c = vk >> 23;
    float4 a0 = {0, 0, 0, 0}, a1 = {0, 0, 0, 0}, a2 = {0, 0, 0, 0}, a3 = {0, 0, 0, 0};
    // sum in ascending original-index order (bit-exact vs reference segment_sum)
    int last = -1;
    for (u32 it = 0; it < c; it++) {
        int mn = 0x7fffffff;
        for (u32 j = 0; j < c; j++) {
            int id = (int)sidx[start + j];
            if (id > last && id < mn) mn = id;
        }
        last = mn;
        const float4* f = (const float4*)(feats + (size_t)mn * 16);
        float4 v0 = f[0], v1 = f[1], v2 = f[2], v3 = f[3];
        a0.x += v0.x; a0.y += v0.y; a0.z += v0.z; a0.w += v0.w;
        a1.x += v1.x; a1.y += v1.y; a1.z += v1.z; a1.w += v1.w;
        a2.x += v2.x; a2.y += v2.y; a2.z += v2.z; a2.w += v2.w;
        a3.x += v3.x; a3.y += v3.y; a3.z += v3.z; a3.w += v3.w;
    }
    float fc = (float)c;
    float4* vf = (float4*)(vox_feats + (size_t)t * 16);
    vf[0] = make_float4(a0.x / fc, a0.y / fc, a0.z / fc, a0.w / fc);
    vf[1] = make_float4(a1.x / fc, a1.y / fc, a1.z / fc, a1.w / fc);
    vf[2] = make_float4(a2.x / fc, a2.y / fc, a2.z / fc, a2.w / fc);
    vf[3] = make_float4(a3.x / fc, a3.y / fc, a3.z / fc, a3.w / fc);
    // reconstruct coords from key
    u32 iv = invrank[kk >> 6];
    u32 tau = iv >> 6;
    u32 c3 = (kk ^ iv) & 63u;
    *(float4*)(vox_coords + (size_t)t * 4) =
        make_float4((float)(tau / 2304u), (float)((tau % 2304u) / 48u),
                    (float)(tau % 48u), (float)c3);
}

extern "C" void kernel_launch(void* const* d_in, const int* in_sizes, int n_in,
                              void* d_out, int out_size, void* d_ws, size_t ws_size,
                              hipStream_t stream) {
    const int* coords = (const int*)d_in[0];
    const float* feats = (const float*)d_in[1];
    int N = in_sizes[0] / 4;

    float* out = (float*)d_out;
    float* vox_feats = out;                      // N*16
    float* vox_coords = out + (size_t)N * 16;    // N*4
    float* v2p = vox_coords + (size_t)N * 4;     // N
    float* nvox = v2p + (size_t)N;               // 1

    char* w = (char*)d_ws;
    u32* pos = (u32*)w;        w += (size_t)NBINS * 4;   // 28.3 MB (counts -> gid map)
    u32* pkey = (u32*)w;       w += (size_t)N * 4;
    u32* sidx = (u32*)w;       w += (size_t)N * 4;
    u64* voxmeta = (u64*)w;    w += (size_t)N * 8;
    u32* vcount = (u32*)w;     w += (size_t)N * 4;
    u32* rank48_d = (u32*)w;   w += (size_t)NTRIP * 4;
    u32* invrank_d = (u32*)w;  w += (size_t)NTRIP * 4;
    u64* lvl2 = (u64*)w;       w += (size_t)4096 * 8;
    u32* nvslot = (u32*)w;     w += 256;

    hipMemcpyAsync(rank48_d, g_rank48, sizeof(g_rank48), hipMemcpyHostToDevice, stream);
    hipMemsetAsync(pos, 0, (size_t)NBINS * 4, stream);
    hipMemsetAsync(vcount, 0, (size_t)N * 4, stream);

    int blocksN = (N + 255) / 256;
    int blocksT = (NTRIP + 255) / 256;

    k_invrank<<<blocksT, 256, 0, stream>>>(rank48_d, invrank_d);
    k_pkeys<<<blocksN, 256, 0, stream>>>(coords, rank48_d, pos, pkey, N);
    k_scan2A<<<NCHUNKS, SCAN_T, 0, stream>>>(pos, lvl2);
    k_scan2_single<<<1, SCAN_T, 0, stream>>>(lvl2, NCHUNKS, nvslot);
    k_scan2B<<<NCHUNKS, SCAN_T, 0, stream>>>(pos, lvl2, voxmeta);
    k_points2<<<blocksN, 256, 0, stream>>>(pkey, pos, voxmeta, vcount, sidx, v2p, N);
    k_vox<<<blocksN, 256, 0, stream>>>(voxmeta, sidx, invrank_d, feats, nvslot,
                                       vox_feats, vox_coords, nvox, N);
}